// Round 6
// baseline (14286.870 us; speedup 1.0000x reference)
//
#include <hip/hip_runtime.h>
#include <hip/hip_bf16.h>

// Problem constants
#define BB 128   // batch
#define TT 1024  // timesteps
#define HH 512   // hidden
#define VV 256   // vocab
#define NBLK 128 // 64 stage1 + 64 stage2 blocks (32 per batch-half each)
#define SENT 0x7F7F7F7Fu   // bf16 0x7F7F = 3.39e38: never a tanh output / 0-state

typedef __attribute__((ext_vector_type(8))) short short8;   // 8 x bf16
typedef __attribute__((ext_vector_type(4))) float floatx4;  // MFMA acc

union AFrag { unsigned long long u[2]; short8 s; };

__device__ __forceinline__ floatx4 mfma16(short8 a, short8 b, floatx4 c) {
    return __builtin_amdgcn_mfma_f32_16x16x32_bf16(a, b, c, 0, 0, 0);
}
__device__ __forceinline__ float sigm(float x) { return 1.0f / (1.0f + __expf(-x)); }
__device__ __forceinline__ float tanh_fast(float x) {
    return 2.0f / (1.0f + __expf(-2.0f * x)) - 1.0f;
}
// Relaxed agent-scope ops: MALL-coherent, no cache writeback/invalidate.
__device__ __forceinline__ unsigned long long ald64(const unsigned long long* p) {
    return __hip_atomic_load(p, __ATOMIC_RELAXED, __HIP_MEMORY_SCOPE_AGENT);
}
__device__ __forceinline__ void ast32(unsigned* p, unsigned v) {
    __hip_atomic_store(p, v, __ATOMIC_RELAXED, __HIP_MEMORY_SCOPE_AGENT);
}
__device__ __forceinline__ int vld(unsigned long long v) {
    return ((unsigned)v != SENT) & ((unsigned)(v >> 32) != SENT);
}

// One-shot canonicalization: fp32 weights -> bf16 ws copies; bias pre-sums; x transpose.
__global__ __launch_bounds__(256) void canon(
    const float* __restrict__ x,
    const float* __restrict__ Whh1, const float* __restrict__ Wih2,
    const float* __restrict__ Whh2, const float* __restrict__ Wlin,
    const float* __restrict__ bih1, const float* __restrict__ bhh1,
    const float* __restrict__ bih2, const float* __restrict__ bhh2,
    __hip_bfloat16* __restrict__ Whh1c, __hip_bfloat16* __restrict__ Wih2c,
    __hip_bfloat16* __restrict__ Whh2c, __hip_bfloat16* __restrict__ Wlinc,
    float* __restrict__ bsum1, float* __restrict__ bsum2,
    float* __restrict__ xT)
{
    const int tid = blockIdx.x * 256 + threadIdx.x;
    const int np  = gridDim.x * 256;
    for (int i = tid; i < 2048 * 512; i += np) {
        Whh1c[i] = __float2bfloat16(Whh1[i]);
        Wih2c[i] = __float2bfloat16(Wih2[i]);
        Whh2c[i] = __float2bfloat16(Whh2[i]);
    }
    for (int i = tid; i < 256 * 512; i += np) Wlinc[i] = __float2bfloat16(Wlin[i]);
    for (int i = tid; i < 2048; i += np) {
        bsum1[i] = bih1[i] + bhh1[i];
        bsum2[i] = bih2[i] + bhh2[i];
    }
    for (int i = tid; i < BB * TT; i += np) {
        int b = i >> 10, t = i & 1023;
        xT[t * BB + b] = x[i];
    }
}

// Persistent dataflow LSTM, sentinel protocol: consumers poll THEIR OWN
// A-fragment words (atomic b64) until sentinel-free — the detecting load IS
// the data load. No fences, no flags, no RMW, no vmcnt drains in the loop.
//   h1all: full array, slot t+1 = h1(t); every address written exactly once.
//   h2ring: 8 slots, slot (t+1)&7 = h2(t). Producer self-re-arms slot (t+5)&7
//   each step (all-to-all k-dim bounds intra-group skew to <=1 step -> safe).
__global__ __launch_bounds__(256, 1) void lstm_persist(
    const float* __restrict__ xT,              // [T][B] fp32
    const float* __restrict__ Wih1,            // [2048] fp32 (IN=1)
    const __hip_bfloat16* __restrict__ Whh1c,  // [2048,512] bf16
    const float* __restrict__ bsum1,           // [2048]
    const __hip_bfloat16* __restrict__ Wih2c,  // [2048,512] bf16
    const __hip_bfloat16* __restrict__ Whh2c,  // [2048,512] bf16
    const float* __restrict__ bsum2,           // [2048]
    unsigned* __restrict__ h2ring,             // [8][B*H/2] u32
    unsigned* __restrict__ h1all,              // [1025][B*H/2] u32
    __hip_bfloat16* __restrict__ h2slots)      // d_out as bf16 slots [B][T][H]
{
    extern __shared__ __hip_bfloat16 lds[];    // stage1: 64 KB; stage2: 128 KB

    const int bid   = blockIdx.x;
    const int stage = bid >> 6;                // 0: layer1, 1: layer2
    const int half  = (bid >> 5) & 1;          // batch half
    const int lb    = bid & 31;
    const int j0    = lb * 16;                 // h-unit tile
    const int b0    = half * 64;               // batch tile
    const int w     = threadIdx.x >> 6;
    const int lane  = threadIdx.x & 63;
    const int q     = lane >> 4, ln = lane & 15;
    const int r0    = b0 + w * 16;

    // ---- stage weights into LDS, fragment-permuted (once) ----
    {
        const __hip_bfloat16* S0 = (stage == 0) ? Whh1c : Wih2c;
        for (int idx = threadIdx.x; idx < 4096; idx += 256) {
            const int g = idx >> 10, kk = (idx >> 6) & 15, l = idx & 63;
            const int lnt = l & 15, qt = l >> 4;
            const size_t src = (size_t)(g * 512 + j0 + lnt) * 512 + kk * 32 + qt * 8;
            *(float4*)(lds + idx * 8) = *(const float4*)(S0 + src);
            if (stage == 1)
                *(float4*)(lds + 32768 + idx * 8) = *(const float4*)(Whh2c + src);
        }
    }
    __syncthreads();   // weights ready; last block-sync in this kernel

    // per-thread step-invariant epilogue constants
    float wv[4], bs[4];
    #pragma unroll
    for (int g = 0; g < 4; ++g) {
        const int j = g * 512 + j0 + ln;
        if (stage == 0) { wv[g] = Wih1[j]; bs[g] = bsum1[j]; }
        else            { wv[g] = 0.0f;    bs[g] = bsum2[j]; }
    }
    float cre[4] = {0.0f, 0.0f, 0.0f, 0.0f};   // register-resident cell state

    const unsigned long long* h1u = (const unsigned long long*)h1all;
    const unsigned long long* h2u = (const unsigned long long*)h2ring;
    const int au = (r0 + ln) * 128 + q * 2;    // A-frag base in u64 units
    const int jc = j0 + (ln & ~1);             // pack: even column of pair
    const int rA = (ln & 1) ? 2 : 0;

    for (int t = 0; t < TT; ++t) {
        floatx4 acc[4];
        #pragma unroll
        for (int g = 0; g < 4; ++g) acc[g] = floatx4{0, 0, 0, 0};
        unsigned pk[4];

        if (stage == 0) {
            // --- poll-load A = h1(t-1) (slot t); detecting load IS the data ---
            const unsigned long long* pA = h1u + (size_t)t * 16384;
            AFrag A0[16];
            for (;;) {
                int ok = 1;
                #pragma unroll
                for (int kk = 0; kk < 16; ++kk) {
                    A0[kk].u[0] = ald64(pA + au + kk * 8);
                    A0[kk].u[1] = ald64(pA + au + kk * 8 + 1);
                    ok &= vld(A0[kk].u[0]) & vld(A0[kk].u[1]);
                }
                if (__all(ok)) break;
                __builtin_amdgcn_s_sleep(2);
            }
            float4 xv4 = *(const float4*)(xT + t * BB + r0 + q * 4);
            #pragma unroll
            for (int kk = 0; kk < 16; ++kk) {
                #pragma unroll
                for (int g = 0; g < 4; ++g)
                    acc[g] = mfma16(A0[kk].s,
                        *(const short8*)(lds + ((g * 16 + kk) * 64 + lane) * 8), acc[g]);
            }
            #pragma unroll
            for (int reg = 0; reg < 4; ++reg) {
                const float xv = ((const float*)&xv4)[reg];
                float gi = acc[0][reg] + xv * wv[0] + bs[0];
                float gf = acc[1][reg] + xv * wv[1] + bs[1];
                float gg = acc[2][reg] + xv * wv[2] + bs[2];
                float go = acc[3][reg] + xv * wv[3] + bs[3];
                float cn = sigm(gf) * cre[reg] + sigm(gi) * tanh_fast(gg);
                cre[reg] = cn;
                float hn = sigm(go) * tanh_fast(cn);
                __hip_bfloat16 hb = __float2bfloat16(hn);
                unsigned short us; __builtin_memcpy(&us, &hb, 2);
                unsigned mine = us;
                unsigned other = (unsigned)__shfl_xor((int)mine, 1, 64);
                pk[reg] = (ln & 1) ? ((other & 0xffffu) | (mine << 16))
                                   : ((mine & 0xffffu) | (other << 16));
            }
            const int bA = r0 + q * 4 + rA;
            unsigned* dst = h1all + (size_t)(t + 1) * 32768;    // h1(t) -> slot t+1
            ast32(dst + ((bA * HH + jc) >> 1),       pk[rA]);
            ast32(dst + (((bA + 1) * HH + jc) >> 1), pk[rA + 1]);
        } else {
            // --- poll-load A0 = h1(t) (slot t+1), A1 = h2(t-1) (ring slot t&7) ---
            const unsigned long long* pA = h1u + (size_t)(t + 1) * 16384;
            const unsigned long long* pB = h2u + (size_t)(t & 7) * 16384;
            AFrag A0[16], A1[16];
            for (;;) {
                int ok = 1;
                #pragma unroll
                for (int kk = 0; kk < 16; ++kk) {
                    A0[kk].u[0] = ald64(pA + au + kk * 8);
                    A0[kk].u[1] = ald64(pA + au + kk * 8 + 1);
                    A1[kk].u[0] = ald64(pB + au + kk * 8);
                    A1[kk].u[1] = ald64(pB + au + kk * 8 + 1);
                    ok &= vld(A0[kk].u[0]) & vld(A0[kk].u[1])
                        & vld(A1[kk].u[0]) & vld(A1[kk].u[1]);
                }
                if (__all(ok)) break;
                __builtin_amdgcn_s_sleep(2);
            }
            #pragma unroll
            for (int kk = 0; kk < 16; ++kk) {
                #pragma unroll
                for (int g = 0; g < 4; ++g)
                    acc[g] = mfma16(A0[kk].s,
                        *(const short8*)(lds + ((g * 16 + kk) * 64 + lane) * 8), acc[g]);
            }
            #pragma unroll
            for (int kk = 0; kk < 16; ++kk) {
                #pragma unroll
                for (int g = 0; g < 4; ++g)
                    acc[g] = mfma16(A1[kk].s,
                        *(const short8*)(lds + 32768 + ((g * 16 + kk) * 64 + lane) * 8), acc[g]);
            }
            #pragma unroll
            for (int reg = 0; reg < 4; ++reg) {
                float gi = acc[0][reg] + bs[0];
                float gf = acc[1][reg] + bs[1];
                float gg = acc[2][reg] + bs[2];
                float go = acc[3][reg] + bs[3];
                float cn = sigm(gf) * cre[reg] + sigm(gi) * tanh_fast(gg);
                cre[reg] = cn;
                float hn = sigm(go) * tanh_fast(cn);
                __hip_bfloat16 hb = __float2bfloat16(hn);
                unsigned short us; __builtin_memcpy(&us, &hb, 2);
                unsigned mine = us;
                unsigned other = (unsigned)__shfl_xor((int)mine, 1, 64);
                pk[reg] = (ln & 1) ? ((other & 0xffffu) | (mine << 16))
                                   : ((mine & 0xffffu) | (other << 16));
            }
            const int bA = r0 + q * 4 + rA;
            const int o0 = (bA * HH + jc) >> 1, o1 = ((bA + 1) * HH + jc) >> 1;
            unsigned* dst = h2ring + (size_t)((t + 1) & 7) * 32768; // h2(t)
            ast32(dst + o0, pk[rA]);
            ast32(dst + o1, pk[rA + 1]);
            unsigned* outs = (unsigned*)h2slots;                    // plain cached
            outs[(((size_t)bA * TT + t) * HH + jc) >> 1]       = pk[rA];
            outs[(((size_t)(bA + 1) * TT + t) * HH + jc) >> 1] = pk[rA + 1];
            // re-arm my words of slot (t+5)&7 for the write at step t+4
            // (skew<=1 within the group: nobody can be reading that slot now)
            unsigned* ra = h2ring + (size_t)((t + 5) & 7) * 32768;
            ast32(ra + o0, SENT);
            ast32(ra + o1, SENT);
        }
    }
}

// In-place linear+softmax over all T*B rows (slot r: 512 bf16 -> 256 fp32).
__global__ __launch_bounds__(256) void lin_softmax(
    const __hip_bfloat16* __restrict__ Wlinc,  // [256,512] bf16
    const float* __restrict__ blin,            // [256] fp32
    float* out)                                // d_out; aliases the bf16 slots
{
    const __hip_bfloat16* slots = (const __hip_bfloat16*)out;
    const int w = threadIdx.x >> 6;
    const int lane = threadIdx.x & 63;
    const int q = lane >> 4, ln = lane & 15;
    const int r0 = blockIdx.x * 64 + w * 16;

    floatx4 acc[16];
    #pragma unroll
    for (int n = 0; n < 16; ++n) acc[n] = floatx4{0, 0, 0, 0};

    const size_t arow = (size_t)(r0 + ln) * HH + q * 8;
    #pragma unroll 4
    for (int kk = 0; kk < 16; ++kk) {
        short8 a = *(const short8*)(slots + arow + kk * 32);
        #pragma unroll
        for (int n = 0; n < 16; ++n) {
            short8 bf = *(const short8*)(Wlinc + (n * 16 + ln) * HH + kk * 32 + q * 8);
            acc[n] = mfma16(a, bf, acc[n]);
        }
    }

    float bl[16];
    #pragma unroll
    for (int n = 0; n < 16; ++n) bl[n] = blin[n * 16 + ln];

    #pragma unroll
    for (int reg = 0; reg < 4; ++reg) {
        float v[16];
        float mx = -3.4e38f;
        #pragma unroll
        for (int n = 0; n < 16; ++n) {
            v[n] = acc[n][reg] + bl[n];
            mx = fmaxf(mx, v[n]);
        }
        #pragma unroll
        for (int m = 1; m < 16; m <<= 1) mx = fmaxf(mx, __shfl_xor(mx, m));
        float sum = 0.0f;
        #pragma unroll
        for (int n = 0; n < 16; ++n) { v[n] = __expf(v[n] - mx); sum += v[n]; }
        #pragma unroll
        for (int m = 1; m < 16; m <<= 1) sum += __shfl_xor(sum, m);
        const float inv = 1.0f / sum;

        const int r = r0 + q * 4 + reg;        // r = b*T + t
        #pragma unroll
        for (int n = 0; n < 16; ++n)
            out[(size_t)r * VV + n * 16 + ln] = v[n] * inv;
    }
}

extern "C" void kernel_launch(void* const* d_in, const int* in_sizes, int n_in,
                              void* d_out, int out_size, void* d_ws, size_t ws_size,
                              hipStream_t stream)
{
    const float* x     = (const float*)d_in[0];
    const float* W_ih1 = (const float*)d_in[1];
    const float* W_hh1 = (const float*)d_in[2];
    const float* b_ih1 = (const float*)d_in[3];
    const float* b_hh1 = (const float*)d_in[4];
    const float* W_ih2 = (const float*)d_in[5];
    const float* W_hh2 = (const float*)d_in[6];
    const float* b_ih2 = (const float*)d_in[7];
    const float* b_hh2 = (const float*)d_in[8];
    const float* W_lin = (const float*)d_in[9];
    const float* b_lin = (const float*)d_in[10];

    char* p = (char*)d_ws;
    unsigned* h2ring = (unsigned*)p;   p += (size_t)8 * 131072;       // 1 MB
    unsigned* h1all  = (unsigned*)p;   p += (size_t)1025 * 131072;    // 134.4 MB
    float* bsum1 = (float*)p;          p += 2048 * 4;
    float* bsum2 = (float*)p;          p += 2048 * 4;
    float* xT    = (float*)p;          p += (size_t)BB * TT * 4;
    __hip_bfloat16* Whh1c = (__hip_bfloat16*)p; p += (size_t)2048 * 512 * 2;
    __hip_bfloat16* Wih2c = (__hip_bfloat16*)p; p += (size_t)2048 * 512 * 2;
    __hip_bfloat16* Whh2c = (__hip_bfloat16*)p; p += (size_t)2048 * 512 * 2;
    __hip_bfloat16* Wlinc = (__hip_bfloat16*)p; p += (size_t)256 * 512 * 2;
    // total ws use ~143 MB (same ballpark as rounds 4-5, proven available)

    // arm sentinels; zero the t=0 state slots (stream-serialized order matters)
    hipMemsetAsync(h2ring, 0x7F, (size_t)8 * 131072, stream);
    hipMemsetAsync(h2ring, 0x00, 131072, stream);                  // h2(-1) = 0
    hipMemsetAsync(h1all,  0x7F, (size_t)1025 * 131072, stream);
    hipMemsetAsync(h1all,  0x00, 131072, stream);                  // h1(-1) = 0

    canon<<<dim3(512), dim3(256), 0, stream>>>(
        x, W_hh1, W_ih2, W_hh2, W_lin, b_ih1, b_hh1, b_ih2, b_hh2,
        Whh1c, Wih2c, Whh2c, Wlinc, bsum1, bsum2, xT);

    const int smem_bytes = 131072;   // 128 KB dynamic LDS
    (void)hipFuncSetAttribute((const void*)lstm_persist,
                              hipFuncAttributeMaxDynamicSharedMemorySize, smem_bytes);

    lstm_persist<<<dim3(NBLK), dim3(256), smem_bytes, stream>>>(
        xT, W_ih1, Whh1c, bsum1, Wih2c, Whh2c, bsum2,
        h2ring, h1all, (__hip_bfloat16*)d_out);

    lin_softmax<<<dim3((TT * BB) / 64), dim3(256), 0, stream>>>(
        Wlinc, b_lin, (float*)d_out);
}